// Round 8
// baseline (657.679 us; speedup 1.0000x reference)
//
#include <hip/hip_runtime.h>
#include <stdint.h>
#include <stddef.h>

#define NROWS 65536
#define EDIM  256
#define NE    1024
#define CAP   24

// d_out element offsets (f32): [loss][z_q_st 16777216][perp][enc 67108864][idx 65536]
static const long long OFF_ZQ   = 1LL;
static const long long OFF_PERP = 16777217LL;
static const long long OFF_ENC  = 16777218LL;
static const long long OFF_IDX  = 83886082LL;

typedef __attribute__((ext_vector_type(8))) short bf16x8;
typedef __attribute__((ext_vector_type(4))) float f32x4;

// RNE float->bf16 (same as R4..R7 passing runs).
__device__ __forceinline__ unsigned short f2bf(float f) {
  unsigned u = __float_as_uint(f);
  return (unsigned short)((u + 0x7FFFu + ((u >> 16) & 1u)) >> 16);
}

// ---------------------------------------------------------------------------
// Kernel 0 (tiny): emb norms + bf16 codebook + hist zero + global emax.
// Bitwise-identical to R5/R7 passing runs.
// ---------------------------------------------------------------------------
__global__ __launch_bounds__(256) void k_emb(const float* __restrict__ emb,
                                             float* __restrict__ enorm,
                                             unsigned short* __restrict__ ebf16,
                                             unsigned int* __restrict__ hist,
                                             int* __restrict__ emaxbits) {
  if (blockIdx.x == 0) {
    for (int i = threadIdx.x; i < NE; i += 256) hist[i] = 0u;
  }
  int er   = blockIdx.x * 4 + (threadIdx.x >> 6);
  int lane = threadIdx.x & 63;
  float4 v = ((const float4*)(emb + (size_t)er * EDIM))[lane];
  ushort4 h;
  h.x = f2bf(v.x); h.y = f2bf(v.y); h.z = f2bf(v.z); h.w = f2bf(v.w);
  ((ushort4*)(ebf16 + (size_t)er * EDIM))[lane] = h;
  float s = v.x * v.x + v.y * v.y + v.z * v.z + v.w * v.w;
#pragma unroll
  for (int m = 1; m < 64; m <<= 1) s += __shfl_xor(s, m);
  if (lane == 0) {
    enorm[er] = s;
    atomicMax(emaxbits, (int)__float_as_uint(s));  // s > 0 -> bits order-monotone
  }
}

// ---------------------------------------------------------------------------
// Kernel 1: bf16-MFMA screen + exact fp32 refine + idx write ONLY.
// (Diagnostic split of R7's k_main: scatter/zero-fill moved out so rocprof
// attributes the 268 us between the latency phase and the streaming phase.)
// All arithmetic chains, orders, tie-breaks bitwise-identical to R5/R7:
//   screen d~ = fmaf(-2, mfma-acc, znorm+enorm), window W=0.025*sqrt(zn*emax)
//   +2e-4 (>=3x analytic bound), monotone-safe emission; exact refine =
//   chained fmaf ascending k over fp32 z,e; (d,idx)-lex min.
// ---------------------------------------------------------------------------
__global__ __launch_bounds__(256, 4) void k_screen(
    const float* __restrict__ z, const float* __restrict__ emb,
    const unsigned short* __restrict__ ebf16,
    const float* __restrict__ enorm,
    const int* __restrict__ emaxbits,
    float* __restrict__ out) {
  __shared__ unsigned short zb[32 * 264];   // 16.9 KB  A bf16, stride 264
  __shared__ float en_s[NE];                // 4 KB
  __shared__ float zn_s[32];
  __shared__ float wr_s[32];
  __shared__ unsigned int rmin_s[32];
  __shared__ unsigned short cand_s[32][CAP];
  __shared__ int ccnt_s[32];
  __shared__ float bestd_s[32][8];
  __shared__ int   besti_s[32][8];

  const int tid   = threadIdx.x;
  const int lane  = tid & 63;
  const int wid   = tid >> 6;          // 0..3
  const int l15   = lane & 15;
  const int l4    = lane >> 4;         // 0..3
  const int rbase = blockIdx.x * 32;

  if (tid < 32) { rmin_s[tid] = 0x7F800000u; ccnt_s[tid] = 0; }
  for (int i = tid; i < NE; i += 256) en_s[i] = enorm[i];

  // ---- prologue: read z rows (fp32), znorm tree (bitwise R2), stage bf16 A.
  // unroll 2: two row-loads in flight (iterations independent; per-row
  // arithmetic unchanged).
  {
#pragma unroll 2
    for (int rr = 0; rr < 8; ++rr) {
      int row_l = wid * 8 + rr;
      float4 v = ((const float4*)(z + (size_t)(rbase + row_l) * EDIM))[lane];
      float s = v.x * v.x + v.y * v.y + v.z * v.z + v.w * v.w;
#pragma unroll
      for (int m = 1; m < 64; m <<= 1) s += __shfl_xor(s, m);
      if (lane == 0) zn_s[row_l] = s;
      ushort4 h;
      h.x = f2bf(v.x); h.y = f2bf(v.y); h.z = f2bf(v.z); h.w = f2bf(v.w);
      ((ushort4*)&zb[row_l * 264])[lane] = h;
    }
  }
  __syncthreads();

  const float emaxf = __uint_as_float((unsigned)*emaxbits);
  if (tid < 32) wr_s[tid] = 0.025f * sqrtf(zn_s[tid] * emaxf) + 2.0e-4f;

  float znr[2][4];
#pragma unroll
  for (int rt = 0; rt < 2; ++rt)
#pragma unroll
    for (int reg = 0; reg < 4; ++reg) znr[rt][reg] = zn_s[rt * 16 + l4 * 4 + reg];

  const unsigned short* pa0 = &zb[l15 * 264 + l4 * 8];
  const unsigned short* pa1 = pa0 + 16 * 264;

  // ---- screen: 4 slabs; 8-chunk unrolled loop, B direct from L2 ----
#pragma unroll 1
  for (int slab = 0; slab < 4; ++slab) {
    f32x4 acc[2][4];
#pragma unroll
    for (int rt = 0; rt < 2; ++rt)
#pragma unroll
      for (int ct = 0; ct < 4; ++ct) acc[rt][ct] = (f32x4){0.f, 0.f, 0.f, 0.f};

    const unsigned short* eb0 =
        ebf16 + (size_t)(slab * 256 + wid * 64 + l15) * EDIM + l4 * 8;
    const unsigned short* eb1 = eb0 + 16 * EDIM;
    const unsigned short* eb2 = eb0 + 32 * EDIM;
    const unsigned short* eb3 = eb0 + 48 * EDIM;

    bf16x8 cb0 = *(const bf16x8*)(eb0);
    bf16x8 cb1 = *(const bf16x8*)(eb1);
    bf16x8 cb2 = *(const bf16x8*)(eb2);
    bf16x8 cb3 = *(const bf16x8*)(eb3);
    bf16x8 ca0 = *(const bf16x8*)(pa0);
    bf16x8 ca1 = *(const bf16x8*)(pa1);

#define MFMA8()                                                            \
    acc[0][0] = __builtin_amdgcn_mfma_f32_16x16x32_bf16(ca0, cb0, acc[0][0], 0, 0, 0); \
    acc[1][0] = __builtin_amdgcn_mfma_f32_16x16x32_bf16(ca1, cb0, acc[1][0], 0, 0, 0); \
    acc[0][1] = __builtin_amdgcn_mfma_f32_16x16x32_bf16(ca0, cb1, acc[0][1], 0, 0, 0); \
    acc[1][1] = __builtin_amdgcn_mfma_f32_16x16x32_bf16(ca1, cb1, acc[1][1], 0, 0, 0); \
    acc[0][2] = __builtin_amdgcn_mfma_f32_16x16x32_bf16(ca0, cb2, acc[0][2], 0, 0, 0); \
    acc[1][2] = __builtin_amdgcn_mfma_f32_16x16x32_bf16(ca1, cb2, acc[1][2], 0, 0, 0); \
    acc[0][3] = __builtin_amdgcn_mfma_f32_16x16x32_bf16(ca0, cb3, acc[0][3], 0, 0, 0); \
    acc[1][3] = __builtin_amdgcn_mfma_f32_16x16x32_bf16(ca1, cb3, acc[1][3], 0, 0, 0);

#define STEP(ch)                                                           \
    {                                                                      \
      bf16x8 nb0 = *(const bf16x8*)(eb0 + ((ch) + 1) * 32);                \
      bf16x8 nb1 = *(const bf16x8*)(eb1 + ((ch) + 1) * 32);                \
      bf16x8 nb2 = *(const bf16x8*)(eb2 + ((ch) + 1) * 32);                \
      bf16x8 nb3 = *(const bf16x8*)(eb3 + ((ch) + 1) * 32);                \
      bf16x8 na0 = *(const bf16x8*)(pa0 + ((ch) + 1) * 32);                \
      bf16x8 na1 = *(const bf16x8*)(pa1 + ((ch) + 1) * 32);                \
      MFMA8();                                                             \
      cb0 = nb0; cb1 = nb1; cb2 = nb2; cb3 = nb3; ca0 = na0; ca1 = na1;    \
    }

    STEP(0) STEP(1) STEP(2) STEP(3) STEP(4) STEP(5) STEP(6)
    MFMA8();
#undef STEP
#undef MFMA8

    // slab row-min (thread over ct, shfl over lane bits 0..3, LDS atomicMin)
#pragma unroll
    for (int rt = 0; rt < 2; ++rt)
#pragma unroll
      for (int reg = 0; reg < 4; ++reg) {
        int row = rt * 16 + l4 * 4 + reg;
        float dm = 3.402823466e+38f;
#pragma unroll
        for (int ct = 0; ct < 4; ++ct) {
          int code = slab * 256 + wid * 64 + ct * 16 + l15;
          float t  = znr[rt][reg] + en_s[code];
          float dt = fmaf(-2.f, acc[rt][ct][reg], t);
          dm = fminf(dm, dt);
        }
#pragma unroll
        for (int m = 1; m < 16; m <<= 1) dm = fminf(dm, __shfl_xor(dm, m));
        if (l15 == 0) atomicMin(&rmin_s[row], __float_as_uint(dm));
      }
    __syncthreads();  // own+prior slab mins merged -> bounded thresholds

    // emission vs running min (monotone: races only ADD false positives)
#pragma unroll
    for (int rt = 0; rt < 2; ++rt)
#pragma unroll
      for (int reg = 0; reg < 4; ++reg) {
        int row = rt * 16 + l4 * 4 + reg;
        float thr = __uint_as_float(rmin_s[row]) + wr_s[row];
#pragma unroll
        for (int ct = 0; ct < 4; ++ct) {
          int code = slab * 256 + wid * 64 + ct * 16 + l15;
          float t  = znr[rt][reg] + en_s[code];
          float dt = fmaf(-2.f, acc[rt][ct][reg], t);
          if (dt <= thr) {
            int p = atomicAdd(&ccnt_s[row], 1);
            if (p < CAP) cand_s[row][p] = (unsigned short)code;
          }
        }
      }
    // no post-emission barrier (monotone-safe)
  }
  __syncthreads();  // all emissions done before refine

  // ---- exact refine: 8 threads per row (bitwise R3..R7 chain) ----
  {
    const int sub  = tid >> 5;         // 0..7
    const int r    = tid & 31;
    const float* zp = z + (size_t)(rbase + r) * EDIM;
    float bd = 3.402823466e+38f;
    int   bi = 0x7FFFFFFF;
    int cnt = ccnt_s[r];
    if (cnt <= CAP) {
      for (int j = sub; j < cnt; j += 8) {
        int c = cand_s[r][j];
        const float* ep = emb + (size_t)c * EDIM;
        float p = 0.f;
#pragma unroll 8
        for (int k = 0; k < 256; ++k) p = fmaf(zp[k], ep[k], p);  // exact chain
        float t = zn_s[r] + en_s[c];
        float d = fmaf(-2.f, p, t);
        if (d < bd || (d == bd && c < bi)) { bd = d; bi = c; }
      }
    } else {  // overflow fallback: exact scan (correctness backstop)
      for (int c = sub; c < NE; c += 8) {
        const float* ep = emb + (size_t)c * EDIM;
        float p = 0.f;
#pragma unroll 8
        for (int k = 0; k < 256; ++k) p = fmaf(zp[k], ep[k], p);
        float t = zn_s[r] + en_s[c];
        float d = fmaf(-2.f, p, t);
        if (d < bd || (d == bd && c < bi)) { bd = d; bi = c; }
      }
    }
    bestd_s[r][sub] = bd;
    besti_s[r][sub] = bi;
  }
  __syncthreads();
  if (tid < 32) {
    float bd = bestd_s[tid][0];
    int   bi = besti_s[tid][0];
#pragma unroll
    for (int j = 1; j < 8; ++j) {
      float od = bestd_s[tid][j];
      int   oi = besti_s[tid][j];
      if (od < bd || (od == bd && oi < bi)) { bd = od; bi = oi; }
    }
    out[(size_t)OFF_IDX + rbase + tid] = (float)bi;  // exact: bi < 2^24
  }
}

// ---------------------------------------------------------------------------
// Kernel 2: streaming scatter. FIXES R5/R7 LATENT BUG: zero-fill now covers
// ALL 32 rows per block (j<32; R5/R7 wrote j<8 = 1/4 of min_encodings and
// "passed" only because 0xAA poison decodes to -3e-13 f32 — WRITE_SIZE
// 139 MB vs mandatory ~340 MB was the tell). NT stores for the 268 MB
// zero-fill + 67 MB z_q_st. STE both-roundings + Spart balanced tree + hist
// atomic + one-hot 1.0 — all bitwise-identical to passing runs.
// ---------------------------------------------------------------------------
__global__ __launch_bounds__(256) void k_scatter(const float* __restrict__ z,
                                                 const float* __restrict__ emb,
                                                 const int* __restrict__ mask,
                                                 float* __restrict__ out,
                                                 unsigned int* __restrict__ hist,
                                                 float* __restrict__ Spart) {
  const int tid   = threadIdx.x;
  const int rbase = blockIdx.x * 32;
  {
    f32x4 zz = (f32x4){0.f, 0.f, 0.f, 0.f};
    f32x4* encz = (f32x4*)(out + OFF_ENC + (size_t)rbase * NE);
#pragma unroll
    for (int j = 0; j < 32; ++j)
      __builtin_nontemporal_store(zz, encz + tid + j * 256);
  }
  __syncthreads();  // zeros drained before one-hot 1.0 writes below

  const int wv = tid >> 6, lane = tid & 63;
#pragma unroll 2
  for (int rr = 0; rr < 8; ++rr) {
    int row_l = wv * 8 + rr;
    int row   = rbase + row_l;
    int idx   = (int)out[(size_t)OFF_IDX + row];  // exact int < 2^24
    float4 zq = ((const float4*)(emb + (size_t)idx * EDIM))[lane];
    float4 zv = ((const float4*)(z + (size_t)row * EDIM))[lane];
    f32x4 st;
    st.x = zv.x + (zq.x - zv.x);
    st.y = zv.y + (zq.y - zv.y);
    st.z = zv.z + (zq.z - zv.z);
    st.w = zv.w + (zq.w - zv.w);
    __builtin_nontemporal_store(st, (f32x4*)(out + OFF_ZQ + (size_t)row * EDIM) + lane);
    float m  = (float)mask[row];
    float dx = __fmul_rn(__fsub_rn(zq.x, zv.x), m);
    float dy = __fmul_rn(__fsub_rn(zq.y, zv.y), m);
    float dz = __fmul_rn(__fsub_rn(zq.z, zv.z), m);
    float dw = __fmul_rn(__fsub_rn(zq.w, zv.w), m);
    float px = __fmul_rn(dx, dx);
    float py = __fmul_rn(dy, dy);
    float pz = __fmul_rn(dz, dz);
    float pw = __fmul_rn(dw, dw);
    float p  = __fadd_rn(__fadd_rn(px, py), __fadd_rn(pz, pw));
#pragma unroll
    for (int s = 1; s < 64; s <<= 1) p = __fadd_rn(p, __shfl_xor(p, s));
    if (lane == 0) {
      Spart[row] = p;
      atomicAdd(&hist[idx], 1u);
      out[(size_t)OFF_ENC + (size_t)row * NE + idx] = 1.0f;
    }
  }
}

// ---------------------------------------------------------------------------
// Kernel 3: finalize loss + perplexity (bitwise-unchanged from passing runs).
// ---------------------------------------------------------------------------
__global__ __launch_bounds__(1024) void k_final(const int* __restrict__ mask,
                                                const unsigned int* __restrict__ hist,
                                                const float* __restrict__ Spart,
                                                float* __restrict__ out) {
  int t = threadIdx.x;  // 1024
  int ms = 0;
  for (int i = t; i < NROWS; i += 1024) ms += mask[i];
  double sp = 0.0;
  for (int i = t; i < NROWS; i += 1024) sp += (double)Spart[i];
  double ent = 0.0;
  {
    int i = t;
    float em = (float)hist[i] * (1.0f / 65536.0f);   // exact
    float lg = logf(em + 1e-10f);
    ent = (double)(em * lg);
  }
#pragma unroll
  for (int m = 1; m < 64; m <<= 1) {
    ms  += __shfl_xor(ms, m);
    sp  += __shfl_xor(sp, m);
    ent += __shfl_xor(ent, m);
  }
  __shared__ double redS[16], redE[16];
  __shared__ int    redM[16];
  int w = t >> 6;
  if ((t & 63) == 0) { redS[w] = sp; redE[w] = ent; redM[w] = ms; }
  __syncthreads();
  if (t == 0) {
    double S = 0.0, E = 0.0; int M = 0;
    for (int i = 0; i < 16; ++i) { S += redS[i]; E += redE[i]; M += redM[i]; }
    float denom = (float)M + 1e-6f;
    float Sf    = (float)S;
    float cl    = Sf / denom;
    out[0] = cl + 0.25f * cl;
    out[(size_t)OFF_PERP] = expf((float)(-E));
  }
}

// ---------------------------------------------------------------------------
extern "C" void kernel_launch(void* const* d_in, const int* in_sizes, int n_in,
                              void* d_out, int out_size, void* d_ws, size_t ws_size,
                              hipStream_t stream) {
  const float* z    = (const float*)d_in[0];
  const int*   mask = (const int*)d_in[1];
  const float* emb  = (const float*)d_in[2];
  float*       out  = (float*)d_out;

  // ws (~795 KB): Spart | enorm | hist | emaxbits(+pad) | ebf16
  float*          Spart    = (float*)d_ws;                       // 65536 f32
  float*          enorm    = Spart + NROWS;                      // 1024 f32
  unsigned int*   hist     = (unsigned int*)(enorm + NE);        // 1024 u32
  int*            emaxbits = (int*)(hist + NE);                  // 1 i32 (+3 pad)
  unsigned short* ebf16    = (unsigned short*)(emaxbits + 4);    // 1024*256 bf16

  k_emb    <<<256,  256, 0, stream>>>(emb, enorm, ebf16, hist, emaxbits);
  k_screen <<<2048, 256, 0, stream>>>(z, emb, ebf16, enorm, emaxbits, out);
  k_scatter<<<2048, 256, 0, stream>>>(z, emb, mask, out, hist, Spart);
  k_final  <<<1,   1024, 0, stream>>>(mask, hist, Spart, out);
}